// Round 5
// baseline (121.658 us; speedup 1.0000x reference)
//
#include <hip/hip_runtime.h>
#include <hip/hip_bf16.h>

#define CC 1024
#define NN 1024
#define BB 2
#define HH 16
#define NT (NN / 64)
#define QSCALE 0.17677669529663687f  // 1/sqrt(32)

typedef short bf16x8 __attribute__((ext_vector_type(8)));
typedef float f32x4  __attribute__((ext_vector_type(4)));

__device__ __forceinline__ f32x4 mfma16(bf16x8 a, bf16x8 b, f32x4 c) {
    return __builtin_amdgcn_mfma_f32_16x16x32_bf16(a, b, c, 0, 0, 0);
}
__device__ __forceinline__ short f2bf(float x) {
    __hip_bfloat16 h = __float2bfloat16(x);
    return *reinterpret_cast<short*>(&h);
}
__device__ __forceinline__ float bf2f(short s) {
    __hip_bfloat16 h;
    *reinterpret_cast<short*>(&h) = s;
    return __bfloat162float(h);
}

// ---------------------------------------------------------------------------
// Fused QKV projection (unchanged). grid (8,16,3), 256 thr.
// ---------------------------------------------------------------------------
__global__ __launch_bounds__(256) void qkv_proj(
    const float* __restrict__ xq, const float* __restrict__ xk, const float* __restrict__ xv,
    const float* __restrict__ wq, const float* __restrict__ wk, const float* __restrict__ wv,
    const float* __restrict__ bq, const float* __restrict__ bk, const float* __restrict__ bv,
    short* __restrict__ qt, short* __restrict__ kt, short* __restrict__ vt)
{
    __shared__ short LD[17408];
    short (*A)[40]  = (short(*)[40])LD;
    short (*Bt)[40] = (short(*)[40])(LD + 128 * 40);
    short (*T)[136] = (short(*)[136])LD;

    const int tid  = threadIdx.x;
    const int lane = tid & 63, wave = tid >> 6;
    const int wr = wave >> 1, wc = wave & 1;
    const int l16 = lane & 15, lk = lane >> 4;
    const int z    = blockIdx.z;
    const int col0 = blockIdx.x * 128;
    const int row0 = blockIdx.y * 128;

    const float* X    = (z == 0) ? xq : (z == 1) ? xk : xv;
    const float* W    = (z == 0) ? wq : (z == 1) ? wk : wv;
    const float* bias = (z == 0) ? bq : (z == 1) ? bk : bv;

    const int str = tid >> 3;
    const int stc = (tid & 7) << 2;

    float4 pa[4], pb[4];
#pragma unroll
    for (int p = 0; p < 4; ++p) {
        pa[p] = *(const float4*)&X[(size_t)(row0 + p * 32 + str) * CC + stc];
        pb[p] = *(const float4*)&W[(size_t)(col0 + p * 32 + str) * CC + stc];
    }

    f32x4 acc[4][4];
#pragma unroll
    for (int i = 0; i < 4; ++i)
#pragma unroll
        for (int j = 0; j < 4; ++j) acc[i][j] = (f32x4){0.f, 0.f, 0.f, 0.f};

    for (int k0 = 0; k0 < CC; k0 += 32) {
#pragma unroll
        for (int p = 0; p < 4; ++p) {
            ushort4 ua = { (unsigned short)f2bf(pa[p].x), (unsigned short)f2bf(pa[p].y),
                           (unsigned short)f2bf(pa[p].z), (unsigned short)f2bf(pa[p].w) };
            *(ushort4*)&A[p * 32 + str][stc] = ua;
            ushort4 ub = { (unsigned short)f2bf(pb[p].x), (unsigned short)f2bf(pb[p].y),
                           (unsigned short)f2bf(pb[p].z), (unsigned short)f2bf(pb[p].w) };
            *(ushort4*)&Bt[p * 32 + str][stc] = ub;
        }
        if (k0 + 32 < CC) {
#pragma unroll
            for (int p = 0; p < 4; ++p) {
                pa[p] = *(const float4*)&X[(size_t)(row0 + p * 32 + str) * CC + k0 + 32 + stc];
                pb[p] = *(const float4*)&W[(size_t)(col0 + p * 32 + str) * CC + k0 + 32 + stc];
            }
        }
        __syncthreads();
        bf16x8 af[4], bw[4];
#pragma unroll
        for (int i = 0; i < 4; ++i) {
            af[i] = *(const bf16x8*)&A[wr * 64 + i * 16 + l16][lk * 8];
            bw[i] = *(const bf16x8*)&Bt[wc * 64 + i * 16 + l16][lk * 8];
        }
#pragma unroll
        for (int mi = 0; mi < 4; ++mi)
#pragma unroll
            for (int nf = 0; nf < 4; ++nf)
                acc[mi][nf] = mfma16(af[mi], bw[nf], acc[mi][nf]);
        __syncthreads();
    }

    if (z <= 1) {
        short* outp = (z == 0) ? qt : kt;
        const float scl = (z == 0) ? QSCALE : 1.f;
#pragma unroll
        for (int mi = 0; mi < 4; ++mi)
#pragma unroll
            for (int q = 0; q < 4; ++q) {
                const int r = row0 + wr * 64 + mi * 16 + lk * 4 + q;
                const int b = r >> 10, n = r & 1023;
#pragma unroll
                for (int nf = 0; nf < 4; ++nf) {
                    const int o = col0 + wc * 64 + nf * 16 + l16;
                    const int h = o >> 6, s = (o >> 5) & 1, ii = o & 31;
                    float y = (acc[mi][nf][q] + bias[o]) * scl;
                    outp[(((size_t)((b * HH + h) * 2 + s)) << 15) + n * 32 + ii] = f2bf(y);
                }
            }
    } else {
#pragma unroll
        for (int mi = 0; mi < 4; ++mi)
#pragma unroll
            for (int nf = 0; nf < 4; ++nf)
#pragma unroll
                for (int q = 0; q < 4; ++q) {
                    const int c = wc * 64 + nf * 16 + l16;
                    const int r = wr * 64 + mi * 16 + lk * 4 + q;
                    T[c][r] = f2bf(acc[mi][nf][q] + bias[col0 + c]);
                }
        __syncthreads();
        const int b  = row0 >> 10, n0 = row0 & 1023;
        const int c  = tid >> 1, half = tid & 1;
        const int oc = col0 + c, h = oc >> 6, d = oc & 63;
        const size_t base = (((size_t)(b * HH + h)) * 64 + d) * NN + n0 + half * 64;
#pragma unroll
        for (int u = 0; u < 8; ++u)
            *(uint4*)&vt[base + u * 8] = *(const uint4*)&T[c][half * 64 + u * 8];
    }
}

// ---------------------------------------------------------------------------
// Attention core: double-buffered K/V, ONE barrier per KV-step.
// grid=(16, 32), 256 thr (4 waves). wave = (s = wave>>1, hf = wave&1).
// Step t: barrier; QK^T(buf[t&1]) -> poly -> packed P-write (wave-private);
//         commit tile t+1 -> buf[t+1&1]; issue global loads tile t+2;
//         PV(buf[t&1]).   commit/load fill the P write->read latency.
// ---------------------------------------------------------------------------
__global__ __launch_bounds__(256) void attn_mfma(
    const short* __restrict__ qt, const short* __restrict__ kt,
    const short* __restrict__ vtg, short* __restrict__ aoh, short* __restrict__ aol)
{
    __shared__ __align__(16) short LDS_[28672];           // 57,344 B
    short* KsB = LDS_;                                    // [2 buf][2 sig][64][40]
    short* VtB = LDS_ + 10240;                            // [2 buf][64][72]
    short* PsB = LDS_ + 19456;                            // [4 wave][32][72]
    float* OsB = (float*)PsB;                             // [64][68] epilogue overlay

#define KS(bf, ss, r, c)  KsB[((((bf) * 2 + (ss)) * 64) + (r)) * 40 + (c)]
#define VT(bf, d, m)      VtB[(((bf) * 64) + (d)) * 72 + (m)]
#define PS(w, n, m)       PsB[((w) * 32 + (n)) * 72 + (m)]
#define OS(n, d)          OsB[(n) * 68 + (d)]

    const int tid  = threadIdx.x;
    const int lane = tid & 63;
    const int wave = tid >> 6;
    const int s  = wave >> 1;
    const int hf = wave & 1;
    const int l16 = lane & 15, lk = lane >> 4;
    const int bh = blockIdx.y;
    const int n0 = blockIdx.x * 64;

    // Q fragments (B-operand of swapped QK^T), register-resident
    bf16x8 qf[2];
#pragma unroll
    for (int nf = 0; nf < 2; ++nf)
        qf[nf] = *(const bf16x8*)&qt[((size_t)(bh * 2 + s) * NN + n0 + hf * 32 + nf * 16 + l16) * 32 + lk * 8];

    uint4 kpf[2], vpf[2];
    auto load_tiles = [&](int m0) {
#pragma unroll
        for (int p = 0; p < 2; ++p) {
            int idx = p * 256 + tid;
            int ss = idx >> 8, j = idx & 255, r = j >> 2, c8 = (j & 3) << 3;
            kpf[p] = *(const uint4*)&kt[((size_t)(bh * 2 + ss) * NN + m0 + r) * 32 + c8];
            int d = idx >> 3, c8v = (idx & 7) << 3;
            vpf[p] = *(const uint4*)&vtg[((size_t)(bh * 64 + d)) * NN + m0 + c8v];
        }
    };
    auto commit_tiles = [&](int bf) {
#pragma unroll
        for (int p = 0; p < 2; ++p) {
            int idx = p * 256 + tid;
            int ss = idx >> 8, j = idx & 255, r = j >> 2, c8 = (j & 3) << 3;
            *(uint4*)&KS(bf, ss, r, c8) = kpf[p];
            int d = idx >> 3, c8v = (idx & 7) << 3;
            *(uint4*)&VT(bf, d, c8v) = vpf[p];
        }
    };

    f32x4 accn[2][4];
#pragma unroll
    for (int nf = 0; nf < 2; ++nf)
#pragma unroll
        for (int df = 0; df < 4; ++df) accn[nf][df] = (f32x4){0.f, 0.f, 0.f, 0.f};
    float den[2] = {0.f, 0.f};

    // prologue: tile0 -> buf0; tile1 in regs
    load_tiles(0);
    commit_tiles(0);
    load_tiles(64);

    for (int t = 0; t < NT; ++t) {
        const int cur = t & 1, nxt = cur ^ 1;
        __syncthreads();   // buf[cur] committed by all; prev readers of buf[nxt] done

        // QK^T (swapped) + polynomial + packed P-write + register denominator
#pragma unroll
        for (int mf = 0; mf < 4; ++mf) {
            bf16x8 kf = *(const bf16x8*)&KS(cur, s, mf * 16 + l16, lk * 8);
#pragma unroll
            for (int nf = 0; nf < 2; ++nf) {
                f32x4 st = mfma16(kf, qf[nf], (f32x4){0.f, 0.f, 0.f, 0.f});
                float p0 = 1.f + st[0] * (1.f + 0.5f * st[0]);
                float p1 = 1.f + st[1] * (1.f + 0.5f * st[1]);
                float p2 = 1.f + st[2] * (1.f + 0.5f * st[2]);
                float p3 = 1.f + st[3] * (1.f + 0.5f * st[3]);
                den[nf] += (p0 + p1) + (p2 + p3);
                short pk[4] = {f2bf(p0), f2bf(p1), f2bf(p2), f2bf(p3)};
                *(uint2*)&PS(wave, nf * 16 + l16, mf * 16 + lk * 4) = *(uint2*)pk;
            }
        }

        // overlap the P write->read latency with staging work
        if (t + 1 < NT) commit_tiles(nxt);
        if (t + 2 < NT) load_tiles((t + 2) * 64);

        // PV (same-wave Ps dependency; compiler lgkmcnt orders)
#pragma unroll
        for (int kb = 0; kb < 2; ++kb) {
            bf16x8 vf[4];
#pragma unroll
            for (int df = 0; df < 4; ++df)
                vf[df] = *(const bf16x8*)&VT(cur, df * 16 + l16, kb * 32 + lk * 8);
#pragma unroll
            for (int nf = 0; nf < 2; ++nf) {
                bf16x8 pf = *(const bf16x8*)&PS(wave, nf * 16 + l16, kb * 32 + lk * 8);
#pragma unroll
                for (int df = 0; df < 4; ++df)
                    accn[nf][df] = mfma16(pf, vf[df], accn[nf][df]);
            }
        }
    }

    // denominator: reduce over lk groups, redistribute per q
    float invq[2][4];
#pragma unroll
    for (int nf = 0; nf < 2; ++nf) {
        float d = den[nf];
        d += __shfl_xor(d, 16, 64);
        d += __shfl_xor(d, 32, 64);
#pragma unroll
        for (int q = 0; q < 4; ++q)
            invq[nf][q] = 0.5f / (__shfl(d, (lane & 48) + lk * 4 + q, 64) + 1e-6f);
    }

    __syncthreads();   // all PV reads of Ps done before Os overlay writes
    if (s == 0) {
#pragma unroll
        for (int nf = 0; nf < 2; ++nf)
#pragma unroll
            for (int q = 0; q < 4; ++q)
#pragma unroll
                for (int df = 0; df < 4; ++df)
                    OS(hf * 32 + nf * 16 + lk * 4 + q, df * 16 + l16) =
                        accn[nf][df][q] * invq[nf][q];
    }
    __syncthreads();
    if (s == 1) {
        const int b = bh >> 4, h = bh & 15;
#pragma unroll
        for (int nf = 0; nf < 2; ++nf)
#pragma unroll
            for (int q = 0; q < 4; ++q) {
                const int n = hf * 32 + nf * 16 + lk * 4 + q;
#pragma unroll
                for (int df = 0; df < 4; ++df) {
                    const int d = df * 16 + l16;
                    float o = OS(n, d) + accn[nf][df][q] * invq[nf][q];
                    size_t addr = ((size_t)b * NN + n0 + n) * CC + h * 64 + d;
                    short hi = f2bf(o);
                    aoh[addr] = hi;
                    aol[addr] = f2bf(o - bf2f(hi));
                }
            }
    }
#undef KS
#undef VT
#undef PS
#undef OS
}

// ---------------------------------------------------------------------------
// Output projection, 3-term split-bf16 (unchanged).
// ---------------------------------------------------------------------------
__global__ __launch_bounds__(256) void wo_proj(
    const short* __restrict__ aoh, const short* __restrict__ aol,
    const float* __restrict__ Wo, const float* __restrict__ bo,
    float* __restrict__ outp)
{
    __shared__ short Ah[64][40], Al[64][40], Wh[64][40], Wl[64][40];

    const int tid  = threadIdx.x;
    const int lane = tid & 63, wave = tid >> 6;
    const int wr = wave >> 1, wc = wave & 1;
    const int l16 = lane & 15, lk = lane >> 4;
    const int col0 = blockIdx.x * 64;
    const int row0 = blockIdx.y * 64;

    const int ar  = tid >> 2, ac8 = (tid & 3) << 3;
    const int wrr = tid >> 3, wc4 = (tid & 7) << 2;

    uint4 ph, pl;
    float4 pw[2];
    ph = *(const uint4*)&aoh[(size_t)(row0 + ar) * CC + ac8];
    pl = *(const uint4*)&aol[(size_t)(row0 + ar) * CC + ac8];
#pragma unroll
    for (int p = 0; p < 2; ++p)
        pw[p] = *(const float4*)&Wo[(size_t)(col0 + p * 32 + wrr) * CC + wc4];

    f32x4 acc[2][2];
#pragma unroll
    for (int i = 0; i < 2; ++i)
#pragma unroll
        for (int j = 0; j < 2; ++j) acc[i][j] = (f32x4){0.f, 0.f, 0.f, 0.f};

    for (int k0 = 0; k0 < CC; k0 += 32) {
        *(uint4*)&Ah[ar][ac8] = ph;
        *(uint4*)&Al[ar][ac8] = pl;
#pragma unroll
        for (int p = 0; p < 2; ++p) {
            float v[4] = {pw[p].x, pw[p].y, pw[p].z, pw[p].w};
            unsigned short hs[4], ls[4];
#pragma unroll
            for (int j = 0; j < 4; ++j) {
                short hv = f2bf(v[j]);
                hs[j] = (unsigned short)hv;
                ls[j] = (unsigned short)f2bf(v[j] - bf2f(hv));
            }
            *(ushort4*)&Wh[p * 32 + wrr][wc4] = (ushort4){hs[0], hs[1], hs[2], hs[3]};
            *(ushort4*)&Wl[p * 32 + wrr][wc4] = (ushort4){ls[0], ls[1], ls[2], ls[3]};
        }
        if (k0 + 32 < CC) {
            ph = *(const uint4*)&aoh[(size_t)(row0 + ar) * CC + k0 + 32 + ac8];
            pl = *(const uint4*)&aol[(size_t)(row0 + ar) * CC + k0 + 32 + ac8];
#pragma unroll
            for (int p = 0; p < 2; ++p)
                pw[p] = *(const float4*)&Wo[(size_t)(col0 + p * 32 + wrr) * CC + k0 + 32 + wc4];
        }
        __syncthreads();
        bf16x8 ah[2], al[2], wh[2], wl[2];
#pragma unroll
        for (int i = 0; i < 2; ++i) {
            ah[i] = *(const bf16x8*)&Ah[wr * 32 + i * 16 + l16][lk * 8];
            al[i] = *(const bf16x8*)&Al[wr * 32 + i * 16 + l16][lk * 8];
            wh[i] = *(const bf16x8*)&Wh[wc * 32 + i * 16 + l16][lk * 8];
            wl[i] = *(const bf16x8*)&Wl[wc * 32 + i * 16 + l16][lk * 8];
        }
#pragma unroll
        for (int mi = 0; mi < 2; ++mi)
#pragma unroll
            for (int nj = 0; nj < 2; ++nj) {
                acc[mi][nj] = mfma16(ah[mi], wh[nj], acc[mi][nj]);
                acc[mi][nj] = mfma16(ah[mi], wl[nj], acc[mi][nj]);
                acc[mi][nj] = mfma16(al[mi], wh[nj], acc[mi][nj]);
            }
        __syncthreads();
    }

#pragma unroll
    for (int mi = 0; mi < 2; ++mi)
#pragma unroll
        for (int q = 0; q < 4; ++q) {
            const int r = row0 + wr * 32 + mi * 16 + lk * 4 + q;
#pragma unroll
            for (int nj = 0; nj < 2; ++nj) {
                const int o = col0 + wc * 32 + nj * 16 + l16;
                outp[(size_t)r * CC + o] = acc[mi][nj][q] + bo[o];
            }
        }
}

extern "C" void kernel_launch(void* const* d_in, const int* in_sizes, int n_in,
                              void* d_out, int out_size, void* d_ws, size_t ws_size,
                              hipStream_t stream) {
    const float* query = (const float*)d_in[0];
    const float* key_  = (const float*)d_in[1];
    const float* value = (const float*)d_in[2];
    const float* Wq = (const float*)d_in[3];
    const float* bq = (const float*)d_in[4];
    const float* Wk = (const float*)d_in[5];
    const float* bk = (const float*)d_in[6];
    const float* Wv = (const float*)d_in[7];
    const float* bv = (const float*)d_in[8];
    const float* Wo = (const float*)d_in[9];
    const float* bo = (const float*)d_in[10];
    float* out = (float*)d_out;

    short* qt  = (short*)d_ws;                 // 4 MB  [b][h][s][n][32]
    short* kt  = qt  + ((size_t)1 << 21);      // 4 MB  [b][h][s][m][32]
    short* vt  = kt  + ((size_t)1 << 21);      // 4 MB  [b][h][d][m]
    short* aoh = vt  + ((size_t)1 << 21);      // 4 MB  attn out hi
    short* aol = aoh + ((size_t)1 << 21);      // 4 MB  attn out lo

    dim3 blk(256);
    qkv_proj<<<dim3(8, 16, 3), blk, 0, stream>>>(query, key_, value, Wq, Wk, Wv,
                                                 bq, bk, bv, qt, kt, vt);
    attn_mfma<<<dim3(16, 32), blk, 0, stream>>>(qt, kt, vt, aoh, aol);
    wo_proj<<<dim3(16, 32), blk, 0, stream>>>(aoh, aol, Wo, bo, out);
}

// Round 6
// 116.372 us; speedup vs baseline: 1.0454x; 1.0454x over previous
//
#include <hip/hip_runtime.h>
#include <hip/hip_bf16.h>

#define CC 1024
#define NN 1024
#define BB 2
#define HH 16
#define NSPLIT 2
#define NSTEP (NN / 64 / NSPLIT)   // 8 KV steps per split block
#define QSCALE 0.17677669529663687f  // 1/sqrt(32)

typedef short bf16x8 __attribute__((ext_vector_type(8)));
typedef float f32x4  __attribute__((ext_vector_type(4)));

__device__ __forceinline__ f32x4 mfma16(bf16x8 a, bf16x8 b, f32x4 c) {
    return __builtin_amdgcn_mfma_f32_16x16x32_bf16(a, b, c, 0, 0, 0);
}
__device__ __forceinline__ short f2bf(float x) {
    __hip_bfloat16 h = __float2bfloat16(x);
    return *reinterpret_cast<short*>(&h);
}
__device__ __forceinline__ float bf2f(short s) {
    __hip_bfloat16 h;
    *reinterpret_cast<short*>(&h) = s;
    return __bfloat162float(h);
}

// ---------------------------------------------------------------------------
// Fused QKV projection (unchanged, proven). grid (8,16,3), 256 thr.
// ---------------------------------------------------------------------------
__global__ __launch_bounds__(256) void qkv_proj(
    const float* __restrict__ xq, const float* __restrict__ xk, const float* __restrict__ xv,
    const float* __restrict__ wq, const float* __restrict__ wk, const float* __restrict__ wv,
    const float* __restrict__ bq, const float* __restrict__ bk, const float* __restrict__ bv,
    short* __restrict__ qt, short* __restrict__ kt, short* __restrict__ vt)
{
    __shared__ short LD[17408];
    short (*A)[40]  = (short(*)[40])LD;
    short (*Bt)[40] = (short(*)[40])(LD + 128 * 40);
    short (*T)[136] = (short(*)[136])LD;

    const int tid  = threadIdx.x;
    const int lane = tid & 63, wave = tid >> 6;
    const int wr = wave >> 1, wc = wave & 1;
    const int l16 = lane & 15, lk = lane >> 4;
    const int z    = blockIdx.z;
    const int col0 = blockIdx.x * 128;
    const int row0 = blockIdx.y * 128;

    const float* X    = (z == 0) ? xq : (z == 1) ? xk : xv;
    const float* W    = (z == 0) ? wq : (z == 1) ? wk : wv;
    const float* bias = (z == 0) ? bq : (z == 1) ? bk : bv;

    const int str = tid >> 3;
    const int stc = (tid & 7) << 2;

    float4 pa[4], pb[4];
#pragma unroll
    for (int p = 0; p < 4; ++p) {
        pa[p] = *(const float4*)&X[(size_t)(row0 + p * 32 + str) * CC + stc];
        pb[p] = *(const float4*)&W[(size_t)(col0 + p * 32 + str) * CC + stc];
    }

    f32x4 acc[4][4];
#pragma unroll
    for (int i = 0; i < 4; ++i)
#pragma unroll
        for (int j = 0; j < 4; ++j) acc[i][j] = (f32x4){0.f, 0.f, 0.f, 0.f};

    for (int k0 = 0; k0 < CC; k0 += 32) {
#pragma unroll
        for (int p = 0; p < 4; ++p) {
            ushort4 ua = { (unsigned short)f2bf(pa[p].x), (unsigned short)f2bf(pa[p].y),
                           (unsigned short)f2bf(pa[p].z), (unsigned short)f2bf(pa[p].w) };
            *(ushort4*)&A[p * 32 + str][stc] = ua;
            ushort4 ub = { (unsigned short)f2bf(pb[p].x), (unsigned short)f2bf(pb[p].y),
                           (unsigned short)f2bf(pb[p].z), (unsigned short)f2bf(pb[p].w) };
            *(ushort4*)&Bt[p * 32 + str][stc] = ub;
        }
        if (k0 + 32 < CC) {
#pragma unroll
            for (int p = 0; p < 4; ++p) {
                pa[p] = *(const float4*)&X[(size_t)(row0 + p * 32 + str) * CC + k0 + 32 + stc];
                pb[p] = *(const float4*)&W[(size_t)(col0 + p * 32 + str) * CC + k0 + 32 + stc];
            }
        }
        __syncthreads();
        bf16x8 af[4], bw[4];
#pragma unroll
        for (int i = 0; i < 4; ++i) {
            af[i] = *(const bf16x8*)&A[wr * 64 + i * 16 + l16][lk * 8];
            bw[i] = *(const bf16x8*)&Bt[wc * 64 + i * 16 + l16][lk * 8];
        }
#pragma unroll
        for (int mi = 0; mi < 4; ++mi)
#pragma unroll
            for (int nf = 0; nf < 4; ++nf)
                acc[mi][nf] = mfma16(af[mi], bw[nf], acc[mi][nf]);
        __syncthreads();
    }

    if (z <= 1) {
        short* outp = (z == 0) ? qt : kt;
        const float scl = (z == 0) ? QSCALE : 1.f;
#pragma unroll
        for (int mi = 0; mi < 4; ++mi)
#pragma unroll
            for (int q = 0; q < 4; ++q) {
                const int r = row0 + wr * 64 + mi * 16 + lk * 4 + q;
                const int b = r >> 10, n = r & 1023;
#pragma unroll
                for (int nf = 0; nf < 4; ++nf) {
                    const int o = col0 + wc * 64 + nf * 16 + l16;
                    const int h = o >> 6, s = (o >> 5) & 1, ii = o & 31;
                    float y = (acc[mi][nf][q] + bias[o]) * scl;
                    outp[(((size_t)((b * HH + h) * 2 + s)) << 15) + n * 32 + ii] = f2bf(y);
                }
            }
    } else {
#pragma unroll
        for (int mi = 0; mi < 4; ++mi)
#pragma unroll
            for (int nf = 0; nf < 4; ++nf)
#pragma unroll
                for (int q = 0; q < 4; ++q) {
                    const int c = wc * 64 + nf * 16 + l16;
                    const int r = wr * 64 + mi * 16 + lk * 4 + q;
                    T[c][r] = f2bf(acc[mi][nf][q] + bias[col0 + c]);
                }
        __syncthreads();
        const int b  = row0 >> 10, n0 = row0 & 1023;
        const int c  = tid >> 1, half = tid & 1;
        const int oc = col0 + c, h = oc >> 6, d = oc & 63;
        const size_t base = (((size_t)(b * HH + h)) * 64 + d) * NN + n0 + half * 64;
#pragma unroll
        for (int u = 0; u < 8; ++u)
            *(uint4*)&vt[base + u * 8] = *(const uint4*)&T[c][half * 64 + u * 8];
    }
}

// ---------------------------------------------------------------------------
// Attention core, split-K over KV. grid=(16 nb, 32 bh, 2 split), 256 thr.
// Round-4 proven single-buffer loop; each block does 8 KV steps of its half.
// Emits fp32 partial numerators (per signal) + partial denominators to ws.
// ---------------------------------------------------------------------------
__global__ __launch_bounds__(256) void attn_split(
    const short* __restrict__ qt, const short* __restrict__ kt,
    const short* __restrict__ vtg, float* __restrict__ pnum, float* __restrict__ pden)
{
    __shared__ __align__(16) short LDS_[18944];           // 37,888 B -> 4 blocks/CU
    short* KsB = LDS_;                                    // [2 sig][64][40]
    short* VtB = LDS_ + 5120;                             // [64][72]
    short* PsB = LDS_ + 9728;                             // [4 wave][32][72]

#define KS(ss, r, c)  KsB[((ss) * 64 + (r)) * 40 + (c)]
#define VT(d, m)      VtB[(d) * 72 + (m)]
#define PS(w, n, m)   PsB[((w) * 32 + (n)) * 72 + (m)]

    const int tid  = threadIdx.x;
    const int lane = tid & 63;
    const int wave = tid >> 6;
    const int s  = wave >> 1;
    const int hf = wave & 1;
    const int l16 = lane & 15, lk = lane >> 4;
    const int bh = blockIdx.y;
    const int n0 = blockIdx.x * 64;
    const int sp = blockIdx.z;
    const int mbase = sp * (NN / NSPLIT);

    // Q fragments (B-operand of swapped QK^T), register-resident
    bf16x8 qf[2];
#pragma unroll
    for (int nf = 0; nf < 2; ++nf)
        qf[nf] = *(const bf16x8*)&qt[((size_t)(bh * 2 + s) * NN + n0 + hf * 32 + nf * 16 + l16) * 32 + lk * 8];

    uint4 kpf[2], vpf[2];
    auto load_tiles = [&](int m0) {
#pragma unroll
        for (int p = 0; p < 2; ++p) {
            int idx = p * 256 + tid;
            int ss = idx >> 8, j = idx & 255, r = j >> 2, c8 = (j & 3) << 3;
            kpf[p] = *(const uint4*)&kt[((size_t)(bh * 2 + ss) * NN + m0 + r) * 32 + c8];
            int d = idx >> 3, c8v = (idx & 7) << 3;
            vpf[p] = *(const uint4*)&vtg[((size_t)(bh * 64 + d)) * NN + m0 + c8v];
        }
    };

    f32x4 accn[2][4];
#pragma unroll
    for (int nf = 0; nf < 2; ++nf)
#pragma unroll
        for (int df = 0; df < 4; ++df) accn[nf][df] = (f32x4){0.f, 0.f, 0.f, 0.f};
    float den[2] = {0.f, 0.f};

    load_tiles(mbase);

    for (int t = 0; t < NSTEP; ++t) {
        // commit prefetched K/V tile to LDS
#pragma unroll
        for (int p = 0; p < 2; ++p) {
            int idx = p * 256 + tid;
            int ss = idx >> 8, j = idx & 255, r = j >> 2, c8 = (j & 3) << 3;
            *(uint4*)&KS(ss, r, c8) = kpf[p];
            int d = idx >> 3, c8v = (idx & 7) << 3;
            *(uint4*)&VT(d, c8v) = vpf[p];
        }
        if (t + 1 < NSTEP) load_tiles(mbase + (t + 1) * 64);
        __syncthreads();

        // QK^T (swapped) + polynomial + packed P-write + register denominator
#pragma unroll
        for (int mf = 0; mf < 4; ++mf) {
            bf16x8 kf = *(const bf16x8*)&KS(s, mf * 16 + l16, lk * 8);
#pragma unroll
            for (int nf = 0; nf < 2; ++nf) {
                f32x4 st = mfma16(kf, qf[nf], (f32x4){0.f, 0.f, 0.f, 0.f});
                float p0 = 1.f + st[0] * (1.f + 0.5f * st[0]);
                float p1 = 1.f + st[1] * (1.f + 0.5f * st[1]);
                float p2 = 1.f + st[2] * (1.f + 0.5f * st[2]);
                float p3 = 1.f + st[3] * (1.f + 0.5f * st[3]);
                den[nf] += (p0 + p1) + (p2 + p3);
                short pk[4] = {f2bf(p0), f2bf(p1), f2bf(p2), f2bf(p3)};
                *(uint2*)&PS(wave, nf * 16 + l16, mf * 16 + lk * 4) = *(uint2*)pk;
            }
        }

        // PV (same-wave Ps dependency; compiler lgkmcnt orders)
#pragma unroll
        for (int kb = 0; kb < 2; ++kb) {
            bf16x8 vf[4];
#pragma unroll
            for (int df = 0; df < 4; ++df)
                vf[df] = *(const bf16x8*)&VT(df * 16 + l16, kb * 32 + lk * 8);
#pragma unroll
            for (int nf = 0; nf < 2; ++nf) {
                bf16x8 pf = *(const bf16x8*)&PS(wave, nf * 16 + l16, kb * 32 + lk * 8);
#pragma unroll
                for (int df = 0; df < 4; ++df)
                    accn[nf][df] = mfma16(pf, vf[df], accn[nf][df]);
            }
        }
        __syncthreads();
    }

    // partial denominator: reduce over lk groups (full reduce done here; dup x4)
    float dsum[2];
#pragma unroll
    for (int nf = 0; nf < 2; ++nf) {
        float d = den[nf];
        d += __shfl_xor(d, 16, 64);
        d += __shfl_xor(d, 32, 64);
        dsum[nf] = d;
    }

    // write partials: pnum[sp][tile][s][n][d], pden[sp][tile][s][n]
    const int tile = bh * 16 + blockIdx.x;
    float* pn = pnum + (((size_t)sp * 512 + tile) * 2 + s) * 64 * 64;
#pragma unroll
    for (int nf = 0; nf < 2; ++nf)
#pragma unroll
        for (int q = 0; q < 4; ++q) {
            const int n = hf * 32 + nf * 16 + lk * 4 + q;
#pragma unroll
            for (int df = 0; df < 4; ++df)
                pn[(size_t)n * 64 + df * 16 + l16] = accn[nf][df][q];
        }
    if (lk == 0) {
        float* pd = pden + (((size_t)sp * 512 + tile) * 2 + s) * 64;
#pragma unroll
        for (int nf = 0; nf < 2; ++nf)
            pd[hf * 32 + nf * 16 + l16] = dsum[nf];
    }
#undef KS
#undef VT
#undef PS
}

// ---------------------------------------------------------------------------
// Combine split partials: out = 0.5 * sum_s (num_s / (den_s + eps)),
// write bf16 hi/lo for the split Wo GEMM. grid 512 (one block per tile).
// ---------------------------------------------------------------------------
__global__ __launch_bounds__(256) void reduce_attn(
    const float* __restrict__ pnum, const float* __restrict__ pden,
    short* __restrict__ aoh, short* __restrict__ aol)
{
    const int tile = blockIdx.x;
    const int bh = tile >> 4, nb = tile & 15;
    const int b = bh >> 4, h = bh & 15, n0 = nb * 64;
    const int tid = threadIdx.x;

    __shared__ float dinv[2][64];
    if (tid < 128) {
        int s = tid >> 6, n = tid & 63;
        float dsum = pden[(((size_t)0 * 512 + tile) * 2 + s) * 64 + n]
                   + pden[(((size_t)1 * 512 + tile) * 2 + s) * 64 + n];
        dinv[s][n] = 0.5f / (dsum + 1e-6f);
    }
    __syncthreads();

    const size_t b00 = (((size_t)0 * 512 + tile) * 2 + 0) * 64 * 64;
    const size_t b01 = (((size_t)0 * 512 + tile) * 2 + 1) * 64 * 64;
    const size_t b10 = (((size_t)1 * 512 + tile) * 2 + 0) * 64 * 64;
    const size_t b11 = (((size_t)1 * 512 + tile) * 2 + 1) * 64 * 64;

#pragma unroll
    for (int u = 0; u < 4; ++u) {
        const int flat = (u * 256 + tid) * 4;
        const int n = flat >> 6, dd = flat & 63;
        float4 v00 = *(const float4*)&pnum[b00 + (size_t)n * 64 + dd];
        float4 v01 = *(const float4*)&pnum[b01 + (size_t)n * 64 + dd];
        float4 v10 = *(const float4*)&pnum[b10 + (size_t)n * 64 + dd];
        float4 v11 = *(const float4*)&pnum[b11 + (size_t)n * 64 + dd];
        const float i0 = dinv[0][n], i1 = dinv[1][n];
        float o[4] = {
            (v00.x + v10.x) * i0 + (v01.x + v11.x) * i1,
            (v00.y + v10.y) * i0 + (v01.y + v11.y) * i1,
            (v00.z + v10.z) * i0 + (v01.z + v11.z) * i1,
            (v00.w + v10.w) * i0 + (v01.w + v11.w) * i1 };
        ushort4 hh, ll;
        unsigned short* ph = &hh.x;
        unsigned short* pl = &ll.x;
#pragma unroll
        for (int j = 0; j < 4; ++j) {
            short hi = f2bf(o[j]);
            ph[j] = (unsigned short)hi;
            pl[j] = (unsigned short)f2bf(o[j] - bf2f(hi));
        }
        const size_t addr = ((size_t)b * NN + n0 + n) * CC + h * 64 + dd;
        *(ushort4*)&aoh[addr] = hh;
        *(ushort4*)&aol[addr] = ll;
    }
}

// ---------------------------------------------------------------------------
// Output projection, 3-term split-bf16 (unchanged, proven).
// ---------------------------------------------------------------------------
__global__ __launch_bounds__(256) void wo_proj(
    const short* __restrict__ aoh, const short* __restrict__ aol,
    const float* __restrict__ Wo, const float* __restrict__ bo,
    float* __restrict__ outp)
{
    __shared__ short Ah[64][40], Al[64][40], Wh[64][40], Wl[64][40];

    const int tid  = threadIdx.x;
    const int lane = tid & 63, wave = tid >> 6;
    const int wr = wave >> 1, wc = wave & 1;
    const int l16 = lane & 15, lk = lane >> 4;
    const int col0 = blockIdx.x * 64;
    const int row0 = blockIdx.y * 64;

    const int ar  = tid >> 2, ac8 = (tid & 3) << 3;
    const int wrr = tid >> 3, wc4 = (tid & 7) << 2;

    uint4 ph, pl;
    float4 pw[2];
    ph = *(const uint4*)&aoh[(size_t)(row0 + ar) * CC + ac8];
    pl = *(const uint4*)&aol[(size_t)(row0 + ar) * CC + ac8];
#pragma unroll
    for (int p = 0; p < 2; ++p)
        pw[p] = *(const float4*)&Wo[(size_t)(col0 + p * 32 + wrr) * CC + wc4];

    f32x4 acc[2][2];
#pragma unroll
    for (int i = 0; i < 2; ++i)
#pragma unroll
        for (int j = 0; j < 2; ++j) acc[i][j] = (f32x4){0.f, 0.f, 0.f, 0.f};

    for (int k0 = 0; k0 < CC; k0 += 32) {
        *(uint4*)&Ah[ar][ac8] = ph;
        *(uint4*)&Al[ar][ac8] = pl;
#pragma unroll
        for (int p = 0; p < 2; ++p) {
            float v[4] = {pw[p].x, pw[p].y, pw[p].z, pw[p].w};
            unsigned short hs[4], ls[4];
#pragma unroll
            for (int j = 0; j < 4; ++j) {
                short hv = f2bf(v[j]);
                hs[j] = (unsigned short)hv;
                ls[j] = (unsigned short)f2bf(v[j] - bf2f(hv));
            }
            *(ushort4*)&Wh[p * 32 + wrr][wc4] = (ushort4){hs[0], hs[1], hs[2], hs[3]};
            *(ushort4*)&Wl[p * 32 + wrr][wc4] = (ushort4){ls[0], ls[1], ls[2], ls[3]};
        }
        if (k0 + 32 < CC) {
            ph = *(const uint4*)&aoh[(size_t)(row0 + ar) * CC + k0 + 32 + ac8];
            pl = *(const uint4*)&aol[(size_t)(row0 + ar) * CC + k0 + 32 + ac8];
#pragma unroll
            for (int p = 0; p < 2; ++p)
                pw[p] = *(const float4*)&Wo[(size_t)(col0 + p * 32 + wrr) * CC + k0 + 32 + wc4];
        }
        __syncthreads();
        bf16x8 ah[2], al[2], wh[2], wl[2];
#pragma unroll
        for (int i = 0; i < 2; ++i) {
            ah[i] = *(const bf16x8*)&Ah[wr * 32 + i * 16 + l16][lk * 8];
            al[i] = *(const bf16x8*)&Al[wr * 32 + i * 16 + l16][lk * 8];
            wh[i] = *(const bf16x8*)&Wh[wc * 32 + i * 16 + l16][lk * 8];
            wl[i] = *(const bf16x8*)&Wl[wc * 32 + i * 16 + l16][lk * 8];
        }
#pragma unroll
        for (int mi = 0; mi < 2; ++mi)
#pragma unroll
            for (int nj = 0; nj < 2; ++nj) {
                acc[mi][nj] = mfma16(ah[mi], wh[nj], acc[mi][nj]);
                acc[mi][nj] = mfma16(ah[mi], wl[nj], acc[mi][nj]);
                acc[mi][nj] = mfma16(al[mi], wh[nj], acc[mi][nj]);
            }
        __syncthreads();
    }

#pragma unroll
    for (int mi = 0; mi < 2; ++mi)
#pragma unroll
        for (int q = 0; q < 4; ++q) {
            const int r = row0 + wr * 32 + mi * 16 + lk * 4 + q;
#pragma unroll
            for (int nj = 0; nj < 2; ++nj) {
                const int o = col0 + wc * 32 + nj * 16 + l16;
                outp[(size_t)r * CC + o] = acc[mi][nj][q] + bo[o];
            }
        }
}

extern "C" void kernel_launch(void* const* d_in, const int* in_sizes, int n_in,
                              void* d_out, int out_size, void* d_ws, size_t ws_size,
                              hipStream_t stream) {
    const float* query = (const float*)d_in[0];
    const float* key_  = (const float*)d_in[1];
    const float* value = (const float*)d_in[2];
    const float* Wq = (const float*)d_in[3];
    const float* bq = (const float*)d_in[4];
    const float* Wk = (const float*)d_in[5];
    const float* bk = (const float*)d_in[6];
    const float* Wv = (const float*)d_in[7];
    const float* bv = (const float*)d_in[8];
    const float* Wo = (const float*)d_in[9];
    const float* bo = (const float*)d_in[10];
    float* out = (float*)d_out;

    short* qt = (short*)d_ws;                      // 4 MB [b][h][s][n][32]
    short* kt = qt + ((size_t)1 << 21);            // 4 MB [b][h][s][m][32]
    short* vt = kt + ((size_t)1 << 21);            // 4 MB [b][h][d][m]
    float* pnum = (float*)(vt + ((size_t)1 << 21));     // 33.5 MB fp32 partial numerators
    float* pden = pnum + (size_t)NSPLIT * 512 * 2 * 64 * 64;  // 0.5 MB fp32 partial denoms
    // aoh/aol overlay qt/kt (dead after attn_split; kernels serialize on stream)
    short* aoh = qt;
    short* aol = kt;

    dim3 blk(256);
    qkv_proj<<<dim3(8, 16, 3), blk, 0, stream>>>(query, key_, value, Wq, Wk, Wv,
                                                 bq, bk, bv, qt, kt, vt);
    attn_split<<<dim3(16, 32, NSPLIT), blk, 0, stream>>>(qt, kt, vt, pnum, pden);
    reduce_attn<<<dim3(512), blk, 0, stream>>>(pnum, pden, aoh, aol);
    wo_proj<<<dim3(16, 32), blk, 0, stream>>>(aoh, aol, Wo, bo, out);
}